// Round 2
// baseline (304.541 us; speedup 1.0000x reference)
//
#include <hip/hip_runtime.h>
#include <math.h>

#define T_LEN 4096
#define B_SZ  512

// emission: fl(fl(fl(-0.5*x)*x) - fl32(0.5*log(2*pi)))
__device__ __forceinline__ float emis(float xv) {
    float a = __fmul_rn(-0.5f, xv);
    float b = __fmul_rn(a, xv);
    return __fsub_rn(b, (float)0.9189385332046727);
}

// ---------------------------------------------------------------------------
// k_init: one tiny block. logA/logAT (numpy pairwise-16 rowsum, fp64 log) into
// workspace global memory, so k_fused's psi waves can read columns via
// wave-uniform pointers -> s_load scalar path (SGPR operands, zero VALU cost).
__global__ __launch_bounds__(256) void k_init(const float* __restrict__ hmm,
                                              float* __restrict__ logA,
                                              float* __restrict__ logAT) {
    const int tid = threadIdx.x;
    const int i = tid >> 4, j = tid & 15;
    const float* row = hmm + i * 16;
    float r[8];
#pragma unroll
    for (int k = 0; k < 8; ++k) r[k] = __fadd_rn(row[k], row[k + 8]);
    float s = __fadd_rn(
        __fadd_rn(__fadd_rn(r[0], r[1]), __fadd_rn(r[2], r[3])),
        __fadd_rn(__fadd_rn(r[4], r[5]), __fadd_rn(r[6], r[7])));
    float la = (float)log((double)row[j]);
    float ls = (float)log((double)s);
    float v = __fsub_rn(la, ls);
    logA[tid] = v;
    logAT[j * 16 + i] = v;
}

// ---------------------------------------------------------------------------
#define DPP_ROR0(K, SRC) __builtin_amdgcn_update_dpp(0, (SRC), 0x120 + (K), 0xF, 0xF, false)
#define M3(x, y, z) fmaxf(fmaxf(x, y), z)

#define ADDPP(DST, K)                                                                 \
    asm("v_add_f32_dpp %0, %1, %2 row_ror:" #K " row_mask:0xf bank_mask:0xf"          \
        : "=v"(DST) : "v"(d), "v"(a[K]))

#define STEPC(ET)                                                                     \
    {                                                                                 \
        float s0 = __fadd_rn(d, a[0]);                                                \
        float s1, s2, s3, s4, s5, s6, s7, s8, s9, s10, s11, s12, s13, s14, s15;       \
        ADDPP(s1, 1);   ADDPP(s2, 2);   ADDPP(s3, 3);   ADDPP(s4, 4);                 \
        ADDPP(s5, 5);   ADDPP(s6, 6);   ADDPP(s7, 7);   ADDPP(s8, 8);                 \
        ADDPP(s9, 9);   ADDPP(s10, 10); ADDPP(s11, 11); ADDPP(s12, 12);               \
        ADDPP(s13, 13); ADDPP(s14, 14); ADDPP(s15, 15);                               \
        float u0 = M3(s0, s1, s2),  u1 = M3(s3, s4, s5),  u2 = M3(s6, s7, s8);        \
        float u3 = M3(s9, s10, s11), u4 = M3(s12, s13, s14);                          \
        float m = fmaxf(M3(u0, u1, u2), M3(u3, u4, s15));                             \
        d = __fadd_rn(m, ET);                                                         \
    }

#define GRP4(QV, SLOTDW)                                                              \
    {                                                                                 \
        float4 dq;                                                                    \
        STEPC(QV.x) dq.x = d; STEPC(QV.y) dq.y = d;                                   \
        STEPC(QV.z) dq.z = d; STEPC(QV.w) dq.w = d;                                   \
        *(float4*)(db + (SLOTDW)) = dq;                                               \
    }

// Byte map application via v_perm — used for boundary chain.
#define PERMSEL(V, Q)                                                                 \
    {                                                                                 \
        int sel_ = (V) & 7;                                                           \
        int lo_, hi_;                                                                 \
        asm("v_perm_b32 %0, %1, %2, %3" : "=v"(lo_) : "v"((Q).y), "v"((Q).x), "v"(sel_)); \
        asm("v_perm_b32 %0, %1, %2, %3" : "=v"(hi_) : "v"((Q).w), "v"((Q).z), "v"(sel_)); \
        V = (((V) & 8) ? hi_ : lo_) & 0xff;                                           \
    }

#define WALK64(BASE, CUR, PRE, POST)                                                  \
    {                                                                                 \
        uint4 m_[8];                                                                  \
        _Pragma("unroll") for (int z_ = 0; z_ < 8; ++z_)                              \
            m_[z_] = *(const uint4*)((BASE) + (63 - z_) * 16);                        \
        for (int r_ = 63; r_ >= 15; r_ -= 8) {                                        \
            uint4 n_[8];                                                              \
            _Pragma("unroll") for (int z_ = 0; z_ < 8; ++z_)                          \
                n_[z_] = *(const uint4*)((BASE) + (r_ - 8 - z_) * 16);                \
            _Pragma("unroll") for (int z_ = 0; z_ < 8; ++z_) {                        \
                PRE(r_ - z_, CUR) PERMSEL(CUR, m_[z_]) POST(r_ - z_, CUR)             \
            }                                                                         \
            _Pragma("unroll") for (int z_ = 0; z_ < 8; ++z_) m_[z_] = n_[z_];         \
        }                                                                             \
        _Pragma("unroll") for (int z_ = 0; z_ < 8; ++z_) {                            \
            PRE(7 - z_, CUR) PERMSEL(CUR, m_[z_]) POST(7 - z_, CUR)                   \
        }                                                                             \
    }

// Nibble-packed map application: row = u64 of 16 nibbles, next = (row>>4*cur)&15.
#define NIBHOP(V, Q) (V) = (int)(((Q) >> ((unsigned)(V) << 2)) & 15ull);

#define NWALK64(BASE, CUR, POST)                                                      \
    {                                                                                 \
        const unsigned long long* bb_ = (BASE);                                       \
        unsigned long long m_[8];                                                     \
        _Pragma("unroll") for (int z_ = 0; z_ < 8; ++z_) m_[z_] = bb_[63 - z_];       \
        for (int r_ = 63; r_ >= 15; r_ -= 8) {                                       \
            unsigned long long n_[8];                                                 \
            _Pragma("unroll") for (int z_ = 0; z_ < 8; ++z_) n_[z_] = bb_[r_ - 8 - z_]; \
            _Pragma("unroll") for (int z_ = 0; z_ < 8; ++z_) {                        \
                NIBHOP(CUR, m_[z_]) POST(r_ - z_, CUR)                                \
            }                                                                         \
            _Pragma("unroll") for (int z_ = 0; z_ < 8; ++z_) m_[z_] = n_[z_];         \
        }                                                                             \
        _Pragma("unroll") for (int z_ = 0; z_ < 8; ++z_) {                            \
            NIBHOP(CUR, m_[z_]) POST(7 - z_, CUR)                                     \
        }                                                                             \
    }

#define NOPX(r, c)
#define EBL_PRE(r, c) eb[r] = (unsigned char)(c);
#define OUT_POST(r, c) ob[r] = (c);

// ---------------------------------------------------------------------------
// k_fused: fwd + psi + chunk maps + backtrace + on-the-fly emissions.
// 2 batches/block, 4 waves.
// Prologue (all threads): emission chunks 0,1 into the Ebuf ring.
// Wave 0 (g<2): Viterbi chains; reads E from LDS ring, writes delta dbuf.
// Waves 1,2: psi of chunk p-1 from dbuf -> nibble-packed pnib. logAT columns
//            come from GLOBAL via wave-uniform pointer -> s_load scalar path
//            (SGPR add operands; LDS columns regressed 18us in R1).
// Wave 3: emissions for chunk p+2 into Ebuf ring (lanes 0-63) + nibble
//         map-walk of chunk p-2 -> Ml (lanes 0-31).
// Tail: argmax + boundary chain + 128 chunk walks writing the path to out.
__global__ __launch_bounds__(256) void k_fused(const float* __restrict__ x,
                                               const float* __restrict__ logA,
                                               const float* __restrict__ logAT,
                                               int* __restrict__ out) {
    __shared__ __align__(16) float dbuf[2][2][16][68];   // 17408 B
    __shared__ unsigned long long pnib[2][64 * 65];      // 66560 B (pitch 65: bank spread)
    __shared__ uint4 Mlv[2][64];                         // 2048 B
    __shared__ unsigned char Ebl[2][64];                 // 128 B
    __shared__ float carry_l[2][16];                     // 128 B
    __shared__ __align__(16) float Ebuf[4][2][64];       // 2048 B (4-deep ring, 2 groups)

    const int tid = threadIdx.x;
    const int wave = tid >> 6;
    const int blk = blockIdx.x;

    // ---- prologue: emission chunks 0 and 1 into the ring ----
    {
        const int cc0 = tid >> 7, gp = (tid >> 6) & 1, l0 = tid & 63;
        Ebuf[cc0][gp][l0] = emis(x[(size_t)(blk * 2 + gp) * T_LEN + 64 * cc0 + l0 + 1]);
    }
    __syncthreads();

    if (wave == 0) {
        asm volatile("s_setprio 3");
        const int j = tid & 15, g = tid >> 4;  // active g<2
        float a[16];
        float d = 0.f;
        float4 q0, q1, q2, q3;
        if (g < 2) {
            const int b = blk * 2 + g;
            a[0] = logA[j * 16 + j];
#define LOADA(K) { int sk = DPP_ROR0(K, j); a[K] = logA[sk * 16 + j]; }
            LOADA(1)  LOADA(2)  LOADA(3)  LOADA(4)  LOADA(5)
            LOADA(6)  LOADA(7)  LOADA(8)  LOADA(9)  LOADA(10)
            LOADA(11) LOADA(12) LOADA(13) LOADA(14) LOADA(15)
#undef LOADA
            float e0 = emis(x[(size_t)b * T_LEN]);
            d = __fadd_rn(logA[j], e0);              // delta0
            const float4* e0p = (const float4*)&Ebuf[0][g][0];
            q0 = e0p[0]; q1 = e0p[1]; q2 = e0p[2]; q3 = e0p[3];
        }
        for (int p = 0; p < 66; ++p) {
            __syncthreads();
            if (p < 64 && g < 2) {
                float* db = &dbuf[p & 1][g][j][0];
                db[64] = d;                           // delta at t = 64p
                const float4* ecur = (const float4*)&Ebuf[p & 3][g][0];
                const float4* enxt = (const float4*)&Ebuf[(p + 1) & 3][g][0];
                if (p < 63) {
#pragma clang loop unroll(disable)
                    for (int ii = 0; ii < 3; ++ii) {
                        GRP4(q0, ii * 16 + 0)  q0 = ecur[(ii + 1) * 4 + 0];
                        GRP4(q1, ii * 16 + 4)  q1 = ecur[(ii + 1) * 4 + 1];
                        GRP4(q2, ii * 16 + 8)  q2 = ecur[(ii + 1) * 4 + 2];
                        GRP4(q3, ii * 16 + 12) q3 = ecur[(ii + 1) * 4 + 3];
                    }
                    // last quad of this chunk; prefetch first quad of chunk p+1
                    // (filled by wave 3 during phase p-1 -> barrier-ordered, no race)
                    GRP4(q0, 48) q0 = enxt[0];
                    GRP4(q1, 52) q1 = enxt[1];
                    GRP4(q2, 56) q2 = enxt[2];
                    GRP4(q3, 60) q3 = enxt[3];
                } else {
#pragma clang loop unroll(disable)
                    for (int ii = 0; ii < 3; ++ii) {
                        GRP4(q0, ii * 16 + 0)  q0 = ecur[(ii + 1) * 4 + 0];
                        GRP4(q1, ii * 16 + 4)  q1 = ecur[(ii + 1) * 4 + 1];
                        GRP4(q2, ii * 16 + 8)  q2 = ecur[(ii + 1) * 4 + 2];
                        GRP4(q3, ii * 16 + 12) q3 = ecur[(ii + 1) * 4 + 3];
                    }
                    GRP4(q0, 48) GRP4(q1, 52) GRP4(q2, 56)      // t=4081..4092
                    STEPC(q3.x) db[60] = d;                      // t=4093
                    STEPC(q3.y) db[61] = d;                      // t=4094
                    STEPC(q3.z) db[62] = d;                      // t=4095
                }
            }
        }
        if (g < 2) carry_l[g][j] = d;
    } else if (wave <= 2) {
        const int g2 = wave - 1;
        const int r = tid & 63;
        for (int p = 0; p < 66; ++p) {
            __syncthreads();
            const int c = p - 1;
            if (c >= 0 && c < 64) {
                const int t2 = 64 * c + 1 + r;
                if (t2 <= T_LEN - 1) {
                    const int q = c & 1;
                    const int rs = (r == 0) ? 64 : (r - 1);
                    float dd[16];
#pragma unroll
                    for (int i = 0; i < 16; ++i) dd[i] = dbuf[q][g2][i][rs];
                    unsigned long long pk = 0ull;
#pragma clang loop unroll(disable)
                    for (int jj = 0; jj < 16; ++jj) {
                        const float* col = logAT + (jj << 4);   // wave-uniform -> s_load
                        float best = __fadd_rn(dd[0], col[0]);
                        int arg = 0;
#pragma unroll
                        for (int i = 1; i < 16; ++i) {
                            float s = __fadd_rn(dd[i], col[i]);
                            if (s > best) arg = i;  // first-wins tie rule
                            best = fmaxf(best, s);
                        }
                        pk |= (unsigned long long)arg << (jj * 4);
                    }
                    pnib[g2][c * 65 + r] = pk;
                } else {  // c==63, r==63: t=4096 absent -> identity map
                    pnib[g2][c * 65 + 63] = 0xFEDCBA9876543210ull;
                }
            }
        }
    } else {
        const int l = tid - 192;
        const int g3 = l >> 4, z = l & 15;
        for (int p = 0; p < 66; ++p) {
            __syncthreads();
            // emissions for chunk p+2 into the ring (2 chunks ahead of wave 0's
            // main reads; 1 ahead of its end-of-chunk prefetch -> race-free)
            const int cc = p + 2;
            if (cc < 64) {
                const int t = 64 * cc + l + 1;
                if (t <= T_LEN - 1) {
                    Ebuf[cc & 3][0][l] = emis(x[(size_t)(blk * 2 + 0) * T_LEN + t]);
                    Ebuf[cc & 3][1][l] = emis(x[(size_t)(blk * 2 + 1) * T_LEN + t]);
                }
            }
            const int c = p - 2;
            if (c >= 0 && l < 32) {
                int cur = z;
                NWALK64(&pnib[g3][c * 65], cur, NOPX)
                ((unsigned char*)&Mlv[g3][c])[z] = (unsigned char)cur;
            }
        }
    }

    // ---- fused backtrace tail (all LDS-resident) ----
    __syncthreads();
    if (tid < 2) {
        const int g = tid;
        float best = carry_l[g][0]; int zT = 0;
#pragma unroll
        for (int i = 1; i < 16; ++i) {
            float s = carry_l[g][i];
            if (s > best) zT = i;
            best = fmaxf(best, s);
        }
        int z = zT;
        unsigned char* eb = &Ebl[g][0];
        WALK64((const unsigned char*)&Mlv[g][0], z, EBL_PRE, NOPX)
    }
    __syncthreads();
    if (tid < 128) {
        const int g = tid >> 6, c = tid & 63;
        int* ob = out + (size_t)(blk * 2 + g) * T_LEN + c * 64;
        int cur = Ebl[g][c];
        NWALK64(&pnib[g][c * 65], cur, OUT_POST)  // chunk63 identity hop writes out[4095]=zT
    }
}

// ---------------------------------------------------------------------------
extern "C" void kernel_launch(void* const* d_in, const int* in_sizes, int n_in,
                              void* d_out, int out_size, void* d_ws, size_t ws_size,
                              hipStream_t stream) {
    (void)in_sizes; (void)n_in; (void)out_size; (void)ws_size;
    const float* x   = (const float*)d_in[0];   // [512][4096] fp32
    const float* hmm = (const float*)d_in[1];   // [64][16][16] fp32 (only [0] used)
    int* out = (int*)d_out;                     // [512][4096] int32

    char* w = (char*)d_ws;
    float* logA  = (float*)w;                                  // 1KB
    float* logAT = (float*)(w + 1024);                         // 1KB

    hipLaunchKernelGGL(k_init, dim3(1), dim3(256), 0, stream, hmm, logA, logAT);
    hipLaunchKernelGGL(k_fused, dim3(B_SZ / 2), dim3(256), 0, stream,
                       x, logA, logAT, out);
}

// Round 3
// 294.004 us; speedup vs baseline: 1.0358x; 1.0358x over previous
//
#include <hip/hip_runtime.h>
#include <math.h>

#define T_LEN 4096
#define B_SZ  512

// emission: fl(fl(fl(-0.5*x)*x) - fl32(0.5*log(2*pi)))
__device__ __forceinline__ float emis(float xv) {
    float a = __fmul_rn(-0.5f, xv);
    float b = __fmul_rn(a, xv);
    return __fsub_rn(b, (float)0.9189385332046727);
}

// ---------------------------------------------------------------------------
#define DPP_ROR0(K, SRC) __builtin_amdgcn_update_dpp(0, (SRC), 0x120 + (K), 0xF, 0xF, false)
#define M3(x, y, z) fmaxf(fmaxf(x, y), z)

#define ADDPP(DST, K)                                                                 \
    asm("v_add_f32_dpp %0, %1, %2 row_ror:" #K " row_mask:0xf bank_mask:0xf"          \
        : "=v"(DST) : "v"(d), "v"(a[K]))

#define STEPC(ET)                                                                     \
    {                                                                                 \
        float s0 = __fadd_rn(d, a[0]);                                                \
        float s1, s2, s3, s4, s5, s6, s7, s8, s9, s10, s11, s12, s13, s14, s15;       \
        ADDPP(s1, 1);   ADDPP(s2, 2);   ADDPP(s3, 3);   ADDPP(s4, 4);                 \
        ADDPP(s5, 5);   ADDPP(s6, 6);   ADDPP(s7, 7);   ADDPP(s8, 8);                 \
        ADDPP(s9, 9);   ADDPP(s10, 10); ADDPP(s11, 11); ADDPP(s12, 12);               \
        ADDPP(s13, 13); ADDPP(s14, 14); ADDPP(s15, 15);                               \
        float u0 = M3(s0, s1, s2),  u1 = M3(s3, s4, s5),  u2 = M3(s6, s7, s8);        \
        float u3 = M3(s9, s10, s11), u4 = M3(s12, s13, s14);                          \
        float m = fmaxf(M3(u0, u1, u2), M3(u3, u4, s15));                             \
        d = __fadd_rn(m, ET);                                                         \
    }

#define GRP4(QV, SLOTDW)                                                              \
    {                                                                                 \
        float4 dq;                                                                    \
        STEPC(QV.x) dq.x = d; STEPC(QV.y) dq.y = d;                                   \
        STEPC(QV.z) dq.z = d; STEPC(QV.w) dq.w = d;                                   \
        *(float4*)(db + (SLOTDW)) = dq;                                               \
    }

// Byte map application via v_perm — used for boundary chain.
#define PERMSEL(V, Q)                                                                 \
    {                                                                                 \
        int sel_ = (V) & 7;                                                           \
        int lo_, hi_;                                                                 \
        asm("v_perm_b32 %0, %1, %2, %3" : "=v"(lo_) : "v"((Q).y), "v"((Q).x), "v"(sel_)); \
        asm("v_perm_b32 %0, %1, %2, %3" : "=v"(hi_) : "v"((Q).w), "v"((Q).z), "v"(sel_)); \
        V = (((V) & 8) ? hi_ : lo_) & 0xff;                                           \
    }

#define WALK64(BASE, CUR, PRE, POST)                                                  \
    {                                                                                 \
        uint4 m_[8];                                                                  \
        _Pragma("unroll") for (int z_ = 0; z_ < 8; ++z_)                              \
            m_[z_] = *(const uint4*)((BASE) + (63 - z_) * 16);                        \
        for (int r_ = 63; r_ >= 15; r_ -= 8) {                                        \
            uint4 n_[8];                                                              \
            _Pragma("unroll") for (int z_ = 0; z_ < 8; ++z_)                          \
                n_[z_] = *(const uint4*)((BASE) + (r_ - 8 - z_) * 16);                \
            _Pragma("unroll") for (int z_ = 0; z_ < 8; ++z_) {                        \
                PRE(r_ - z_, CUR) PERMSEL(CUR, m_[z_]) POST(r_ - z_, CUR)             \
            }                                                                         \
            _Pragma("unroll") for (int z_ = 0; z_ < 8; ++z_) m_[z_] = n_[z_];         \
        }                                                                             \
        _Pragma("unroll") for (int z_ = 0; z_ < 8; ++z_) {                            \
            PRE(7 - z_, CUR) PERMSEL(CUR, m_[z_]) POST(7 - z_, CUR)                   \
        }                                                                             \
    }

// Nibble-packed map application: row = u64 of 16 nibbles, next = (row>>4*cur)&15.
#define NIBHOP(V, Q) (V) = (int)(((Q) >> ((unsigned)(V) << 2)) & 15ull);

#define NWALK64(BASE, CUR, POST)                                                      \
    {                                                                                 \
        const unsigned long long* bb_ = (BASE);                                       \
        unsigned long long m_[8];                                                     \
        _Pragma("unroll") for (int z_ = 0; z_ < 8; ++z_) m_[z_] = bb_[63 - z_];       \
        for (int r_ = 63; r_ >= 15; r_ -= 8) {                                       \
            unsigned long long n_[8];                                                 \
            _Pragma("unroll") for (int z_ = 0; z_ < 8; ++z_) n_[z_] = bb_[r_ - 8 - z_]; \
            _Pragma("unroll") for (int z_ = 0; z_ < 8; ++z_) {                        \
                NIBHOP(CUR, m_[z_]) POST(r_ - z_, CUR)                                \
            }                                                                         \
            _Pragma("unroll") for (int z_ = 0; z_ < 8; ++z_) m_[z_] = n_[z_];         \
        }                                                                             \
        _Pragma("unroll") for (int z_ = 0; z_ < 8; ++z_) {                            \
            NIBHOP(CUR, m_[z_]) POST(7 - z_, CUR)                                     \
        }                                                                             \
    }

#define NOPX(r, c)
#define EBL_PRE(r, c) eb[r] = (unsigned char)(c);
#define OUT_POST(r, c) ob[r] = (c);

// psi column operand: wave-uniform scalar via v_readlane from a preloaded VGPR.
// Zero memory ops in the phase loop (R1's LDS reads cost ~21us; s_load needed a
// second kernel costing ~30us of dispatch overhead). All indices compile-time.
#define RLF(V, L) __int_as_float(__builtin_amdgcn_readlane(__float_as_int(V), (L)))

#define PSI_I(I, V, BL)                                                               \
    {                                                                                 \
        float s_ = __fadd_rn(dd[I], RLF(V, (BL) + (I)));                              \
        if (s_ > best) arg = I;  /* first-wins tie rule */                            \
        best = fmaxf(best, s_);                                                       \
    }

#define PSI_J(JJ, V)                                                                  \
    {                                                                                 \
        float best = __fadd_rn(dd[0], RLF(V, (((JJ) & 3) * 16) + 0));                 \
        int arg = 0;                                                                  \
        PSI_I(1, V, ((JJ) & 3) * 16)  PSI_I(2, V, ((JJ) & 3) * 16)                    \
        PSI_I(3, V, ((JJ) & 3) * 16)  PSI_I(4, V, ((JJ) & 3) * 16)                    \
        PSI_I(5, V, ((JJ) & 3) * 16)  PSI_I(6, V, ((JJ) & 3) * 16)                    \
        PSI_I(7, V, ((JJ) & 3) * 16)  PSI_I(8, V, ((JJ) & 3) * 16)                    \
        PSI_I(9, V, ((JJ) & 3) * 16)  PSI_I(10, V, ((JJ) & 3) * 16)                   \
        PSI_I(11, V, ((JJ) & 3) * 16) PSI_I(12, V, ((JJ) & 3) * 16)                   \
        PSI_I(13, V, ((JJ) & 3) * 16) PSI_I(14, V, ((JJ) & 3) * 16)                   \
        PSI_I(15, V, ((JJ) & 3) * 16)                                                 \
        pk |= (unsigned long long)arg << ((JJ) * 4);                                  \
    }

// ---------------------------------------------------------------------------
// Single fused kernel. 2 batches/block, 4 waves (one per SIMD).
// Prologue (all threads): logA/logAT into LDS (bit-exact: pairwise-16 rowsum,
// fp64 log) + emission chunks 0,1 into the Ebuf ring.
// Wave 0 (g<2): Viterbi chains; E from LDS ring, delta into dbuf.
// Waves 1,2: psi of chunk p-1 -> nibble-packed pnib. logAT columns live in
//            4 VGPRs/lane; per-phase v_readlane (asm barrier pins them
//            in-loop so LLVM can't hoist 256 readlanes into SGPR spills).
// Wave 3: emissions for chunk p+2 into Ebuf ring + nibble map-walk of
//         chunk p-2 -> Ml.
// Tail: argmax + boundary chain + 128 chunk walks writing the path to out.
__global__ __launch_bounds__(256) void k_fused(const float* __restrict__ x,
                                               const float* __restrict__ hmm,
                                               int* __restrict__ out) {
    __shared__ __align__(16) float dbuf[2][2][16][68];   // 17408 B
    __shared__ unsigned long long pnib[2][64 * 65];      // 66560 B (pitch 65: bank spread)
    __shared__ uint4 Mlv[2][64];                         // 2048 B
    __shared__ unsigned char Ebl[2][64];                 // 128 B
    __shared__ float carry_l[2][16];                     // 128 B
    __shared__ float logA_l[256];                        // 1024 B
    __shared__ float logAT_l[256];                       // 1024 B
    __shared__ __align__(16) float Ebuf[4][2][64];       // 2048 B (4-deep ring, 2 groups)

    const int tid = threadIdx.x;
    const int wave = tid >> 6;
    const int blk = blockIdx.x;

    // ---- prologue: logA/logAT (exact k_init arithmetic) + emission chunks 0,1 ----
    {
        const int pi = tid >> 4, pj = tid & 15;
        const float* row = hmm + pi * 16;
        float r8[8];
#pragma unroll
        for (int k = 0; k < 8; ++k) r8[k] = __fadd_rn(row[k], row[k + 8]);
        float s = __fadd_rn(
            __fadd_rn(__fadd_rn(r8[0], r8[1]), __fadd_rn(r8[2], r8[3])),
            __fadd_rn(__fadd_rn(r8[4], r8[5]), __fadd_rn(r8[6], r8[7])));
        float la = (float)log((double)row[pj]);
        float ls = (float)log((double)s);
        float v = __fsub_rn(la, ls);
        logA_l[tid] = v;
        logAT_l[pj * 16 + pi] = v;
        const int cc0 = tid >> 7, gp = (tid >> 6) & 1, l0 = tid & 63;
        Ebuf[cc0][gp][l0] = emis(x[(size_t)(blk * 2 + gp) * T_LEN + 64 * cc0 + l0 + 1]);
    }
    __syncthreads();

    if (wave == 0) {
        asm volatile("s_setprio 3");
        const int j = tid & 15, g = tid >> 4;  // active g<2
        float a[16];
        float d = 0.f;
        float4 q0, q1, q2, q3;
        if (g < 2) {
            a[0] = logA_l[j * 16 + j];
#define LOADA(K) { int sk = DPP_ROR0(K, j); a[K] = logA_l[sk * 16 + j]; }
            LOADA(1)  LOADA(2)  LOADA(3)  LOADA(4)  LOADA(5)
            LOADA(6)  LOADA(7)  LOADA(8)  LOADA(9)  LOADA(10)
            LOADA(11) LOADA(12) LOADA(13) LOADA(14) LOADA(15)
#undef LOADA
            const int b = blk * 2 + g;
            float e0 = emis(x[(size_t)b * T_LEN]);
            d = __fadd_rn(logA_l[j], e0);            // delta0
            const float4* e0p = (const float4*)&Ebuf[0][g][0];
            q0 = e0p[0]; q1 = e0p[1]; q2 = e0p[2]; q3 = e0p[3];
        }
        for (int p = 0; p < 66; ++p) {
            __syncthreads();
            if (p < 64 && g < 2) {
                float* db = &dbuf[p & 1][g][j][0];
                db[64] = d;                           // delta at t = 64p
                const float4* ecur = (const float4*)&Ebuf[p & 3][g][0];
                const float4* enxt = (const float4*)&Ebuf[(p + 1) & 3][g][0];
                if (p < 63) {
#pragma clang loop unroll(disable)
                    for (int ii = 0; ii < 3; ++ii) {
                        GRP4(q0, ii * 16 + 0)  q0 = ecur[(ii + 1) * 4 + 0];
                        GRP4(q1, ii * 16 + 4)  q1 = ecur[(ii + 1) * 4 + 1];
                        GRP4(q2, ii * 16 + 8)  q2 = ecur[(ii + 1) * 4 + 2];
                        GRP4(q3, ii * 16 + 12) q3 = ecur[(ii + 1) * 4 + 3];
                    }
                    // last quad of this chunk; prefetch first quad of chunk p+1
                    // (filled by wave 3 during phase p-1 -> barrier-ordered, no race)
                    GRP4(q0, 48) q0 = enxt[0];
                    GRP4(q1, 52) q1 = enxt[1];
                    GRP4(q2, 56) q2 = enxt[2];
                    GRP4(q3, 60) q3 = enxt[3];
                } else {
#pragma clang loop unroll(disable)
                    for (int ii = 0; ii < 3; ++ii) {
                        GRP4(q0, ii * 16 + 0)  q0 = ecur[(ii + 1) * 4 + 0];
                        GRP4(q1, ii * 16 + 4)  q1 = ecur[(ii + 1) * 4 + 1];
                        GRP4(q2, ii * 16 + 8)  q2 = ecur[(ii + 1) * 4 + 2];
                        GRP4(q3, ii * 16 + 12) q3 = ecur[(ii + 1) * 4 + 3];
                    }
                    GRP4(q0, 48) GRP4(q1, 52) GRP4(q2, 56)      // t=4081..4092
                    STEPC(q3.x) db[60] = d;                      // t=4093
                    STEPC(q3.y) db[61] = d;                      // t=4094
                    STEPC(q3.z) db[62] = d;                      // t=4095
                }
            }
        }
        if (g < 2) carry_l[g][j] = d;
    } else if (wave <= 2) {
        const int g2 = wave - 1;
        const int r = tid & 63;
        // preload logAT into 4 VGPRs/lane: vq[q] holds logAT_l[q*64 + lane]
        float vq0 = logAT_l[r];
        float vq1 = logAT_l[64 + r];
        float vq2 = logAT_l[128 + r];
        float vq3 = logAT_l[192 + r];
        for (int p = 0; p < 66; ++p) {
            __syncthreads();
            const int c = p - 1;
            if (c >= 0 && c < 64) {
                const int t2 = 64 * c + 1 + r;
                if (t2 <= T_LEN - 1) {
                    const int q = c & 1;
                    const int rs = (r == 0) ? 64 : (r - 1);
                    float dd[16];
#pragma unroll
                    for (int i = 0; i < 16; ++i) dd[i] = dbuf[q][g2][i][rs];
                    // pin vq* as loop-variant: blocks hoisting of the readlanes
                    asm volatile("" : "+v"(vq0), "+v"(vq1), "+v"(vq2), "+v"(vq3));
                    unsigned long long pk = 0ull;
                    PSI_J(0, vq0)  PSI_J(1, vq0)  PSI_J(2, vq0)  PSI_J(3, vq0)
                    PSI_J(4, vq1)  PSI_J(5, vq1)  PSI_J(6, vq1)  PSI_J(7, vq1)
                    PSI_J(8, vq2)  PSI_J(9, vq2)  PSI_J(10, vq2) PSI_J(11, vq2)
                    PSI_J(12, vq3) PSI_J(13, vq3) PSI_J(14, vq3) PSI_J(15, vq3)
                    pnib[g2][c * 65 + r] = pk;
                } else {  // c==63, r==63: t=4096 absent -> identity map
                    pnib[g2][c * 65 + 63] = 0xFEDCBA9876543210ull;
                }
            }
        }
    } else {
        const int l = tid - 192;
        const int g3 = l >> 4, z = l & 15;
        for (int p = 0; p < 66; ++p) {
            __syncthreads();
            // emissions for chunk p+2 into the ring (2 chunks ahead of wave 0's
            // main reads; 1 ahead of its end-of-chunk prefetch -> race-free)
            const int cc = p + 2;
            if (cc < 64) {
                const int t = 64 * cc + l + 1;
                if (t <= T_LEN - 1) {
                    Ebuf[cc & 3][0][l] = emis(x[(size_t)(blk * 2 + 0) * T_LEN + t]);
                    Ebuf[cc & 3][1][l] = emis(x[(size_t)(blk * 2 + 1) * T_LEN + t]);
                }
            }
            const int c = p - 2;
            if (c >= 0 && l < 32) {
                int cur = z;
                NWALK64(&pnib[g3][c * 65], cur, NOPX)
                ((unsigned char*)&Mlv[g3][c])[z] = (unsigned char)cur;
            }
        }
    }

    // ---- fused backtrace tail (all LDS-resident) ----
    __syncthreads();
    if (tid < 2) {
        const int g = tid;
        float best = carry_l[g][0]; int zT = 0;
#pragma unroll
        for (int i = 1; i < 16; ++i) {
            float s = carry_l[g][i];
            if (s > best) zT = i;
            best = fmaxf(best, s);
        }
        int z = zT;
        unsigned char* eb = &Ebl[g][0];
        WALK64((const unsigned char*)&Mlv[g][0], z, EBL_PRE, NOPX)
    }
    __syncthreads();
    if (tid < 128) {
        const int g = tid >> 6, c = tid & 63;
        int* ob = out + (size_t)(blk * 2 + g) * T_LEN + c * 64;
        int cur = Ebl[g][c];
        NWALK64(&pnib[g][c * 65], cur, OUT_POST)  // chunk63 identity hop writes out[4095]=zT
    }
}

// ---------------------------------------------------------------------------
extern "C" void kernel_launch(void* const* d_in, const int* in_sizes, int n_in,
                              void* d_out, int out_size, void* d_ws, size_t ws_size,
                              hipStream_t stream) {
    (void)in_sizes; (void)n_in; (void)out_size; (void)d_ws; (void)ws_size;
    const float* x   = (const float*)d_in[0];   // [512][4096] fp32
    const float* hmm = (const float*)d_in[1];   // [64][16][16] fp32 (only [0] used)
    int* out = (int*)d_out;                     // [512][4096] int32

    hipLaunchKernelGGL(k_fused, dim3(B_SZ / 2), dim3(256), 0, stream, x, hmm, out);
}

// Round 4
// 289.448 us; speedup vs baseline: 1.0521x; 1.0157x over previous
//
#include <hip/hip_runtime.h>
#include <math.h>

#define T_LEN 4096
#define B_SZ  512
#define CH    128          // chunk length (steps per phase)
#define NCH   32           // chunks = T_LEN / CH
#define PITCH 129          // pnib row pitch (bank spread)
#define PHASES 34          // NCH + 2 pipeline stages

// emission: fl(fl(fl(-0.5*x)*x) - fl32(0.5*log(2*pi)))
__device__ __forceinline__ float emis(float xv) {
    float a = __fmul_rn(-0.5f, xv);
    float b = __fmul_rn(a, xv);
    return __fsub_rn(b, (float)0.9189385332046727);
}

// ---------------------------------------------------------------------------
#define DPP_ROR0(K, SRC) __builtin_amdgcn_update_dpp(0, (SRC), 0x120 + (K), 0xF, 0xF, false)
#define M3(x, y, z) fmaxf(fmaxf(x, y), z)

#define ADDPP(DST, K)                                                                 \
    asm("v_add_f32_dpp %0, %1, %2 row_ror:" #K " row_mask:0xf bank_mask:0xf"          \
        : "=v"(DST) : "v"(d), "v"(a[K]))

#define STEPC(ET)                                                                     \
    {                                                                                 \
        float s0 = __fadd_rn(d, a[0]);                                                \
        float s1, s2, s3, s4, s5, s6, s7, s8, s9, s10, s11, s12, s13, s14, s15;       \
        ADDPP(s1, 1);   ADDPP(s2, 2);   ADDPP(s3, 3);   ADDPP(s4, 4);                 \
        ADDPP(s5, 5);   ADDPP(s6, 6);   ADDPP(s7, 7);   ADDPP(s8, 8);                 \
        ADDPP(s9, 9);   ADDPP(s10, 10); ADDPP(s11, 11); ADDPP(s12, 12);               \
        ADDPP(s13, 13); ADDPP(s14, 14); ADDPP(s15, 15);                               \
        float u0 = M3(s0, s1, s2),  u1 = M3(s3, s4, s5),  u2 = M3(s6, s7, s8);        \
        float u3 = M3(s9, s10, s11), u4 = M3(s12, s13, s14);                          \
        float m = fmaxf(M3(u0, u1, u2), M3(u3, u4, s15));                             \
        d = __fadd_rn(m, ET);                                                         \
    }

#define GRP4(QV, SLOTDW)                                                              \
    {                                                                                 \
        float4 dq;                                                                    \
        STEPC(QV.x) dq.x = d; STEPC(QV.y) dq.y = d;                                   \
        STEPC(QV.z) dq.z = d; STEPC(QV.w) dq.w = d;                                   \
        *(float4*)(db + (SLOTDW)) = dq;                                               \
    }

// Byte map application via v_perm — used for boundary chain.
#define PERMSEL(V, Q)                                                                 \
    {                                                                                 \
        int sel_ = (V) & 7;                                                           \
        int lo_, hi_;                                                                 \
        asm("v_perm_b32 %0, %1, %2, %3" : "=v"(lo_) : "v"((Q).y), "v"((Q).x), "v"(sel_)); \
        asm("v_perm_b32 %0, %1, %2, %3" : "=v"(hi_) : "v"((Q).w), "v"((Q).z), "v"(sel_)); \
        V = (((V) & 8) ? hi_ : lo_) & 0xff;                                           \
    }

// Generic byte map-walk: rows START..0, 8-row preload pipeline.
#define WALKN(BASE, CUR, PRE, POST, START)                                            \
    {                                                                                 \
        uint4 m_[8];                                                                  \
        _Pragma("unroll") for (int z_ = 0; z_ < 8; ++z_)                              \
            m_[z_] = *(const uint4*)((BASE) + ((START) - z_) * 16);                   \
        for (int r_ = (START); r_ >= 15; r_ -= 8) {                                   \
            uint4 n_[8];                                                              \
            _Pragma("unroll") for (int z_ = 0; z_ < 8; ++z_)                          \
                n_[z_] = *(const uint4*)((BASE) + (r_ - 8 - z_) * 16);                \
            _Pragma("unroll") for (int z_ = 0; z_ < 8; ++z_) {                        \
                PRE(r_ - z_, CUR) PERMSEL(CUR, m_[z_]) POST(r_ - z_, CUR)             \
            }                                                                         \
            _Pragma("unroll") for (int z_ = 0; z_ < 8; ++z_) m_[z_] = n_[z_];         \
        }                                                                             \
        _Pragma("unroll") for (int z_ = 0; z_ < 8; ++z_) {                            \
            PRE(7 - z_, CUR) PERMSEL(CUR, m_[z_]) POST(7 - z_, CUR)                   \
        }                                                                             \
    }

// Nibble-packed map application: row = u64 of 16 nibbles, next = (row>>4*cur)&15.
#define NIBHOP(V, Q) (V) = (int)(((Q) >> ((unsigned)(V) << 2)) & 15ull);

// Generic nibble map-walk: rows START..0, 8-row preload pipeline.
#define NWALKN(BASE, CUR, POST, START)                                                \
    {                                                                                 \
        const unsigned long long* bb_ = (BASE);                                       \
        unsigned long long m_[8];                                                     \
        _Pragma("unroll") for (int z_ = 0; z_ < 8; ++z_) m_[z_] = bb_[(START) - z_];  \
        for (int r_ = (START); r_ >= 15; r_ -= 8) {                                   \
            unsigned long long n_[8];                                                 \
            _Pragma("unroll") for (int z_ = 0; z_ < 8; ++z_) n_[z_] = bb_[r_ - 8 - z_]; \
            _Pragma("unroll") for (int z_ = 0; z_ < 8; ++z_) {                        \
                NIBHOP(CUR, m_[z_]) POST(r_ - z_, CUR)                                \
            }                                                                         \
            _Pragma("unroll") for (int z_ = 0; z_ < 8; ++z_) m_[z_] = n_[z_];         \
        }                                                                             \
        _Pragma("unroll") for (int z_ = 0; z_ < 8; ++z_) {                            \
            NIBHOP(CUR, m_[z_]) POST(7 - z_, CUR)                                     \
        }                                                                             \
    }

#define NOPX(r, c)
#define EBL_PRE(r, c) eb[r] = (unsigned char)(c);
#define OUT_POST(r, c) ob[r] = (c);

// psi column operand: wave-uniform scalar via v_readlane from a preloaded VGPR.
// Zero memory ops in the phase loop. All indices compile-time.
#define RLF(V, L) __int_as_float(__builtin_amdgcn_readlane(__float_as_int(V), (L)))

// Dual-row psi: one readlane per (jj,i), shared by rows A and B.
#define PSI2_I(I, V, BL)                                                              \
    {                                                                                 \
        float cs_ = RLF(V, (BL) + (I));                                               \
        float sA_ = __fadd_rn(ddA[I], cs_);                                           \
        if (sA_ > bestA) argA = I;  /* first-wins tie rule */                         \
        bestA = fmaxf(bestA, sA_);                                                    \
        float sB_ = __fadd_rn(ddB[I], cs_);                                           \
        if (sB_ > bestB) argB = I;                                                    \
        bestB = fmaxf(bestB, sB_);                                                    \
    }

#define PSI2_J(JJ, V)                                                                 \
    {                                                                                 \
        float c0_ = RLF(V, (((JJ) & 3) * 16) + 0);                                    \
        float bestA = __fadd_rn(ddA[0], c0_); int argA = 0;                           \
        float bestB = __fadd_rn(ddB[0], c0_); int argB = 0;                           \
        PSI2_I(1, V, ((JJ) & 3) * 16)  PSI2_I(2, V, ((JJ) & 3) * 16)                  \
        PSI2_I(3, V, ((JJ) & 3) * 16)  PSI2_I(4, V, ((JJ) & 3) * 16)                  \
        PSI2_I(5, V, ((JJ) & 3) * 16)  PSI2_I(6, V, ((JJ) & 3) * 16)                  \
        PSI2_I(7, V, ((JJ) & 3) * 16)  PSI2_I(8, V, ((JJ) & 3) * 16)                  \
        PSI2_I(9, V, ((JJ) & 3) * 16)  PSI2_I(10, V, ((JJ) & 3) * 16)                 \
        PSI2_I(11, V, ((JJ) & 3) * 16) PSI2_I(12, V, ((JJ) & 3) * 16)                 \
        PSI2_I(13, V, ((JJ) & 3) * 16) PSI2_I(14, V, ((JJ) & 3) * 16)                 \
        PSI2_I(15, V, ((JJ) & 3) * 16)                                                \
        pkA |= (unsigned long long)argA << ((JJ) * 4);                                \
        pkB |= (unsigned long long)argB << ((JJ) * 4);                                \
    }

// ---------------------------------------------------------------------------
// Single fused kernel, chunk = 128 (34 phases instead of 66: halves barrier
// count and per-phase fixed overhead; chain/phase ~6800cyc vs psi ~4400).
// 2 batches/block, 4 waves (one per SIMD).
// Prologue: logA/logAT into LDS (bit-exact fp64-log) + E chunks 0,1 into ring.
// Wave 0 (g<2): Viterbi chains; E from LDS ring, delta into dbuf.
// Waves 1,2: psi of chunk p-1, 2 rows/lane -> nibble-packed pnib; logAT via
//            per-phase v_readlane from 4 preloaded VGPRs (asm-pinned in-loop).
// Wave 3: emissions for chunk p+2 into ring + nibble map-walk of chunk p-2.
// Tail: argmax + boundary chain (32 hops) + 64 chunk walks writing out.
__global__ __launch_bounds__(256) void k_fused(const float* __restrict__ x,
                                               const float* __restrict__ hmm,
                                               int* __restrict__ out) {
    __shared__ __align__(16) float dbuf[2][2][16][132];  // 33792 B (slot 128 = carry)
    __shared__ unsigned long long pnib[2][NCH * PITCH];  // 66048 B
    __shared__ uint4 Mlv[2][NCH];                        // 1024 B
    __shared__ unsigned char Ebl[2][NCH];                // 64 B
    __shared__ float carry_l[2][16];                     // 128 B
    __shared__ float logA_l[256];                        // 1024 B
    __shared__ float logAT_l[256];                       // 1024 B
    __shared__ __align__(16) float Ebuf[4][2][CH];       // 4096 B (4-deep ring)

    const int tid = threadIdx.x;
    const int wave = tid >> 6;
    const int blk = blockIdx.x;

    // ---- prologue: logA/logAT (bit-exact) + emission chunks 0,1 ----
    {
        const int pi = tid >> 4, pj = tid & 15;
        const float* row = hmm + pi * 16;
        float r8[8];
#pragma unroll
        for (int k = 0; k < 8; ++k) r8[k] = __fadd_rn(row[k], row[k + 8]);
        float s = __fadd_rn(
            __fadd_rn(__fadd_rn(r8[0], r8[1]), __fadd_rn(r8[2], r8[3])),
            __fadd_rn(__fadd_rn(r8[4], r8[5]), __fadd_rn(r8[6], r8[7])));
        float la = (float)log((double)row[pj]);
        float ls = (float)log((double)s);
        float v = __fsub_rn(la, ls);
        logA_l[tid] = v;
        logAT_l[pj * 16 + pi] = v;
        // E chunks 0,1: 512 values / 256 threads = 2 each (t <= 256, no bound check)
        const int cc0 = tid >> 7, gp = (tid >> 6) & 1, l0 = tid & 63;
        const size_t xb = (size_t)(blk * 2 + gp) * T_LEN + CH * cc0 + l0 + 1;
        Ebuf[cc0][gp][l0]      = emis(x[xb]);
        Ebuf[cc0][gp][l0 + 64] = emis(x[xb + 64]);
    }
    __syncthreads();

    if (wave == 0) {
        asm volatile("s_setprio 3");
        const int j = tid & 15, g = tid >> 4;  // active g<2
        float a[16];
        float d = 0.f;
        float4 q0, q1, q2, q3;
        if (g < 2) {
            a[0] = logA_l[j * 16 + j];
#define LOADA(K) { int sk = DPP_ROR0(K, j); a[K] = logA_l[sk * 16 + j]; }
            LOADA(1)  LOADA(2)  LOADA(3)  LOADA(4)  LOADA(5)
            LOADA(6)  LOADA(7)  LOADA(8)  LOADA(9)  LOADA(10)
            LOADA(11) LOADA(12) LOADA(13) LOADA(14) LOADA(15)
#undef LOADA
            const int b = blk * 2 + g;
            float e0 = emis(x[(size_t)b * T_LEN]);
            d = __fadd_rn(logA_l[j], e0);            // delta0
            const float4* e0p = (const float4*)&Ebuf[0][g][0];
            q0 = e0p[0]; q1 = e0p[1]; q2 = e0p[2]; q3 = e0p[3];
        }
        for (int p = 0; p < PHASES; ++p) {
            __syncthreads();
            if (p < NCH && g < 2) {
                float* db = &dbuf[p & 1][g][j][0];
                db[128] = d;                          // delta at t = 128p (carry)
                const float4* ecur = (const float4*)&Ebuf[p & 3][g][0];
                const float4* enxt = (const float4*)&Ebuf[(p + 1) & 3][g][0];
                if (p < NCH - 1) {
#pragma clang loop unroll(disable)
                    for (int ii = 0; ii < 7; ++ii) {
                        GRP4(q0, ii * 16 + 0)  q0 = ecur[(ii + 1) * 4 + 0];
                        GRP4(q1, ii * 16 + 4)  q1 = ecur[(ii + 1) * 4 + 1];
                        GRP4(q2, ii * 16 + 8)  q2 = ecur[(ii + 1) * 4 + 2];
                        GRP4(q3, ii * 16 + 12) q3 = ecur[(ii + 1) * 4 + 3];
                    }
                    // last quad-group of this chunk; prefetch chunk p+1
                    // (filled by wave 3 during phase p-1 -> barrier-ordered)
                    GRP4(q0, 112) q0 = enxt[0];
                    GRP4(q1, 116) q1 = enxt[1];
                    GRP4(q2, 120) q2 = enxt[2];
                    GRP4(q3, 124) q3 = enxt[3];
                } else {
#pragma clang loop unroll(disable)
                    for (int ii = 0; ii < 7; ++ii) {
                        GRP4(q0, ii * 16 + 0)  q0 = ecur[(ii + 1) * 4 + 0];
                        GRP4(q1, ii * 16 + 4)  q1 = ecur[(ii + 1) * 4 + 1];
                        GRP4(q2, ii * 16 + 8)  q2 = ecur[(ii + 1) * 4 + 2];
                        GRP4(q3, ii * 16 + 12) q3 = ecur[(ii + 1) * 4 + 3];
                    }
                    GRP4(q0, 112) GRP4(q1, 116) GRP4(q2, 120)    // t=4081..4092
                    STEPC(q3.x) db[124] = d;                      // t=4093
                    STEPC(q3.y) db[125] = d;                      // t=4094
                    STEPC(q3.z) db[126] = d;                      // t=4095
                }
            }
        }
        if (g < 2) carry_l[g][j] = d;
    } else if (wave <= 2) {
        const int g2 = wave - 1;
        const int r = tid & 63;
        // preload logAT into 4 VGPRs/lane: vqN holds logAT_l[N*64 + lane]
        float vq0 = logAT_l[r];
        float vq1 = logAT_l[64 + r];
        float vq2 = logAT_l[128 + r];
        float vq3 = logAT_l[192 + r];
        for (int p = 0; p < PHASES; ++p) {
            __syncthreads();
            const int c = p - 1;
            if (c >= 0 && c < NCH) {
                const int q = c & 1;
                const int rsA = (r == 0) ? 128 : (r - 1);
                const int rsB = r + 63;
                float ddA[16], ddB[16];
#pragma unroll
                for (int i = 0; i < 16; ++i) {
                    ddA[i] = dbuf[q][g2][i][rsA];
                    ddB[i] = dbuf[q][g2][i][rsB];
                }
                // pin vq* as loop-variant: blocks hoisting of the readlanes
                asm volatile("" : "+v"(vq0), "+v"(vq1), "+v"(vq2), "+v"(vq3));
                unsigned long long pkA = 0ull, pkB = 0ull;
                PSI2_J(0, vq0)  PSI2_J(1, vq0)  PSI2_J(2, vq0)  PSI2_J(3, vq0)
                PSI2_J(4, vq1)  PSI2_J(5, vq1)  PSI2_J(6, vq1)  PSI2_J(7, vq1)
                PSI2_J(8, vq2)  PSI2_J(9, vq2)  PSI2_J(10, vq2) PSI2_J(11, vq2)
                PSI2_J(12, vq3) PSI2_J(13, vq3) PSI2_J(14, vq3) PSI2_J(15, vq3)
                // c==NCH-1, rowB==127: t=4096 absent -> identity map
                if (c == NCH - 1 && r == 63) pkB = 0xFEDCBA9876543210ull;
                pnib[g2][c * PITCH + r]      = pkA;
                pnib[g2][c * PITCH + r + 64] = pkB;
            }
        }
    } else {
        const int l = tid - 192;
        const int g3 = l >> 4, z = l & 15;
        for (int p = 0; p < PHASES; ++p) {
            __syncthreads();
            // emissions for chunk p+2 into the ring (2 chunks ahead of wave 0's
            // main reads; 1 ahead of its end-of-chunk prefetch -> race-free)
            const int cc = p + 2;
            if (cc < NCH) {
                const int t1 = CH * cc + l + 1;
                const int t2 = t1 + 64;
                Ebuf[cc & 3][0][l] = emis(x[(size_t)(blk * 2 + 0) * T_LEN + t1]);
                Ebuf[cc & 3][1][l] = emis(x[(size_t)(blk * 2 + 1) * T_LEN + t1]);
                if (t2 <= T_LEN - 1) {
                    Ebuf[cc & 3][0][l + 64] = emis(x[(size_t)(blk * 2 + 0) * T_LEN + t2]);
                    Ebuf[cc & 3][1][l + 64] = emis(x[(size_t)(blk * 2 + 1) * T_LEN + t2]);
                }
            }
            const int c = p - 2;
            if (c >= 0 && l < 32) {
                int cur = z;
                NWALKN(&pnib[g3][c * PITCH], cur, NOPX, 127)
                ((unsigned char*)&Mlv[g3][c])[z] = (unsigned char)cur;
            }
        }
    }

    // ---- fused backtrace tail (all LDS-resident) ----
    __syncthreads();
    if (tid < 2) {
        const int g = tid;
        float best = carry_l[g][0]; int zT = 0;
#pragma unroll
        for (int i = 1; i < 16; ++i) {
            float s = carry_l[g][i];
            if (s > best) zT = i;
            best = fmaxf(best, s);
        }
        int z = zT;
        unsigned char* eb = &Ebl[g][0];
        WALKN((const unsigned char*)&Mlv[g][0], z, EBL_PRE, NOPX, NCH - 1)
    }
    __syncthreads();
    if (tid < 64) {
        const int g = tid >> 5, c = tid & 31;
        int* ob = out + (size_t)(blk * 2 + g) * T_LEN + c * CH;
        int cur = Ebl[g][c];
        NWALKN(&pnib[g][c * PITCH], cur, OUT_POST, 127)  // last-chunk identity hop writes out[4095]=zT
    }
}

// ---------------------------------------------------------------------------
extern "C" void kernel_launch(void* const* d_in, const int* in_sizes, int n_in,
                              void* d_out, int out_size, void* d_ws, size_t ws_size,
                              hipStream_t stream) {
    (void)in_sizes; (void)n_in; (void)out_size; (void)d_ws; (void)ws_size;
    const float* x   = (const float*)d_in[0];   // [512][4096] fp32
    const float* hmm = (const float*)d_in[1];   // [64][16][16] fp32 (only [0] used)
    int* out = (int*)d_out;                     // [512][4096] int32

    hipLaunchKernelGGL(k_fused, dim3(B_SZ / 2), dim3(256), 0, stream, x, hmm, out);
}